// Round 7
// baseline (552.949 us; speedup 1.0000x reference)
//
#include <hip/hip_runtime.h>
#include <math.h>

// Problem constants (fixed by the reference: B=256, D=131072, H=128)
constexpr int B_ = 256;
constexpr int D_ = 131072;
constexpr int BPR = 8;                           // blocks per row -> 2048 blocks = 8/CU exact residency
constexpr int TPB = 256;                         // threads per reduce block
constexpr int F4_PER_BLOCK = D_ / 4 / BPR;       // 4096 float4 per block per stream
constexpr int NBATCH = F4_PER_BLOCK / TPB;       // 16 iterations, 1 float4/stream/iter

// Native vector type so __builtin_nontemporal_load is applicable (HIP's
// float4 is a class type; clang's builtin needs a scalar/vector).
typedef float f32x4 __attribute__((ext_vector_type(4)));

__device__ __forceinline__ f32x4 nt_load(const f32x4* __restrict__ p) {
    return __builtin_nontemporal_load(p);
}

__device__ __forceinline__ float gelu_exact(float x) {
    // jax.nn.gelu(approximate=False) = 0.5*x*(1+erf(x/sqrt(2)))
    return 0.5f * x * (1.0f + erff(x * 0.7071067811865476f));
}

// ---------------------------------------------------------------------------
// Kernel 1: streaming reduction. Each block handles a 16384-element chunk of
// one row across all 5 arrays, producing 8 partial sums:
//   s0=|d|^2 s1=|v|^2 s2=|fs|^2 s3=|ft|^2 s4=v.d s5=fs.ft s6=v.fs s7=v.ft
//
// History:
//   v3: (256,8) + forced 10-load batch -> scratch spill (WRITE 457 MB), 281us.
//   v4: spill fixed, occ 70%, dur ~180us @ 3.7 TB/s aggregate (same as 46%
//       occ round 0) -> occupancy falsified as the limiter.
//   v5: nontemporal loads: dur 121us, 5.55 TB/s aggregate (9.1 B/cyc/CU).
//       FETCH unchanged (L3 still serves half) — nt un-jammed L1/L2
//       allocation, not the L3 mix.
//   v6: unroll 2 -> 4. VGPR=32 shows only ~5 loads held in flight; give the
//       scheduler 20 independent NT loads per window to close the remaining
//       11% to the measured ~10.2 B/cyc/CU load-path ceiling (m13).
//       Tripwire: WRITE_SIZE must stay ~4 MB (no spill).
// ---------------------------------------------------------------------------
__global__ __launch_bounds__(TPB, 8) void invariant_reduce(
    const float* __restrict__ x,
    const float* __restrict__ xr,
    const float* __restrict__ fs,
    const float* __restrict__ ft,
    const float* __restrict__ v,
    float* __restrict__ partials)
{
    const int blk = blockIdx.x;
    const int row = blk / BPR;
    const int chunk = blk % BPR;
    const int tid = threadIdx.x;

    const size_t base = (size_t)row * D_ + (size_t)chunk * (F4_PER_BLOCK * 4);
    const f32x4* __restrict__ x4  = (const f32x4*)(x  + base);
    const f32x4* __restrict__ xr4 = (const f32x4*)(xr + base);
    const f32x4* __restrict__ fs4 = (const f32x4*)(fs + base);
    const f32x4* __restrict__ ft4 = (const f32x4*)(ft + base);
    const f32x4* __restrict__ v4  = (const f32x4*)(v  + base);

    float s0 = 0.f, s1 = 0.f, s2 = 0.f, s3 = 0.f;
    float s4 = 0.f, s5 = 0.f, s6 = 0.f, s7 = 0.f;

    #pragma unroll 4
    for (int it = 0; it < NBATCH; ++it) {
        const int i = it * TPB + tid;
        const f32x4 a = nt_load(&x4[i]);
        const f32x4 b = nt_load(&xr4[i]);
        const f32x4 c = nt_load(&fs4[i]);
        const f32x4 t = nt_load(&ft4[i]);
        const f32x4 w = nt_load(&v4[i]);

        #define ACC(aa, bb, cc, tt, ww)                              \
        {                                                            \
            const float dd = (bb) - (aa);                            \
            s0 = fmaf(dd, dd, s0);                                   \
            s1 = fmaf((ww), (ww), s1);                               \
            s2 = fmaf((cc), (cc), s2);                               \
            s3 = fmaf((tt), (tt), s3);                               \
            s4 = fmaf((ww), dd, s4);                                 \
            s5 = fmaf((cc), (tt), s5);                               \
            s6 = fmaf((ww), (cc), s6);                               \
            s7 = fmaf((ww), (tt), s7);                               \
        }
        ACC(a.x, b.x, c.x, t.x, w.x);
        ACC(a.y, b.y, c.y, t.y, w.y);
        ACC(a.z, b.z, c.z, t.z, w.z);
        ACC(a.w, b.w, c.w, t.w, w.w);
        #undef ACC
    }

    // 64-lane wave reduction for all 8 accumulators
    #pragma unroll
    for (int off = 32; off > 0; off >>= 1) {
        s0 += __shfl_down(s0, off);
        s1 += __shfl_down(s1, off);
        s2 += __shfl_down(s2, off);
        s3 += __shfl_down(s3, off);
        s4 += __shfl_down(s4, off);
        s5 += __shfl_down(s5, off);
        s6 += __shfl_down(s6, off);
        s7 += __shfl_down(s7, off);
    }

    __shared__ float red[TPB / 64][8];
    const int wave = tid >> 6;
    const int lane = tid & 63;
    if (lane == 0) {
        red[wave][0] = s0; red[wave][1] = s1; red[wave][2] = s2; red[wave][3] = s3;
        red[wave][4] = s4; red[wave][5] = s5; red[wave][6] = s6; red[wave][7] = s7;
    }
    __syncthreads();
    if (tid < 8) {
        const float r = red[0][tid] + red[1][tid] + red[2][tid] + red[3][tid];
        partials[(size_t)blk * 8 + tid] = r;
    }
}

// ---------------------------------------------------------------------------
// Kernel 2: one block (128 threads) per row. Sum the partials, form the 8
// invariants, then run the MLP head entirely in LDS/registers.
// ---------------------------------------------------------------------------
__device__ __forceinline__ float block_sum_128(float val, float* scratch2, int tid) {
    #pragma unroll
    for (int off = 32; off > 0; off >>= 1) val += __shfl_down(val, off);
    const int wave = tid >> 6;
    if ((tid & 63) == 0) scratch2[wave] = val;
    __syncthreads();
    const float r = scratch2[0] + scratch2[1];
    __syncthreads();
    return r;
}

__global__ __launch_bounds__(128) void mlp_head(
    const float* __restrict__ partials,
    const float* __restrict__ inv_scales,
    const float* __restrict__ equilibrium,
    const float* __restrict__ gain,
    const float* __restrict__ W1, const float* __restrict__ b1,
    const float* __restrict__ ln_w, const float* __restrict__ ln_b,
    const float* __restrict__ W2, const float* __restrict__ b2,
    const float* __restrict__ W3, const float* __restrict__ b3,
    const float* __restrict__ W4, const float* __restrict__ b4,
    float* __restrict__ out)
{
    const int row = blockIdx.x;
    const int tid = threadIdx.x;

    __shared__ float sums[8];
    __shared__ float s[8];
    __shared__ float h1[128];
    __shared__ float h2[128];
    __shared__ float h3[64];
    __shared__ float scratch[2];

    // Sum the per-chunk partials for this row.
    if (tid < 8) {
        float acc = 0.f;
        const float* p = partials + (size_t)row * BPR * 8 + tid;
        #pragma unroll
        for (int bch = 0; bch < BPR; ++bch) acc += p[bch * 8];
        sums[tid] = acc;
    }
    __syncthreads();

    // Invariants (exactly the reference's _invariants math).
    if (tid < 8) {
        const float eps = 1e-8f;
        const float dn = sqrtf(sums[0]) + eps;
        const float vn = sqrtf(sums[1]) + eps;
        const float sn = sqrtf(sums[2]) + eps;
        const float tn = sqrtf(sums[3]) + eps;
        float val;
        switch (tid) {
            case 0: val = log1pf(dn); break;
            case 1: val = log1pf(vn); break;
            case 2: val = sums[4] / (vn * dn); break;
            case 3: val = sums[5] / (sn * tn); break;
            case 4: val = sums[6] / (vn * sn); break;
            case 5: val = sums[7] / (vn * tn); break;
            case 6: val = log1pf(vn * vn + dn * dn); break;
            default: val = logf(tn / sn); break;
        }
        s[tid] = val * inv_scales[tid];
    }
    __syncthreads();

    // h = s @ W1 + b1  (W1 is [8,128]) ; thread tid owns column tid.
    float acc = b1[tid];
    #pragma unroll
    for (int k = 0; k < 8; ++k) acc = fmaf(s[k], W1[k * 128 + tid], acc);

    // LayerNorm over the 128 columns (two-pass).
    const float mu  = block_sum_128(acc, scratch, tid) * (1.f / 128.f);
    const float dev = acc - mu;
    const float var = block_sum_128(dev * dev, scratch, tid) * (1.f / 128.f);
    const float xn  = dev * rsqrtf(var + 1e-5f) * ln_w[tid] + ln_b[tid];
    h1[tid] = gelu_exact(xn);
    __syncthreads();

    // h2 = gelu(h1 @ W2 + b2), W2 is [128,128]
    float acc2 = b2[tid];
    #pragma unroll 8
    for (int k = 0; k < 128; ++k) acc2 = fmaf(h1[k], W2[k * 128 + tid], acc2);
    h2[tid] = gelu_exact(acc2);
    __syncthreads();

    // h3 = gelu(h2 @ W3 + b3), W3 is [128,64]
    if (tid < 64) {
        float acc3 = b3[tid];
        #pragma unroll 8
        for (int k = 0; k < 128; ++k) acc3 = fmaf(h2[k], W3[k * 64 + tid], acc3);
        h3[tid] = gelu_exact(acc3);
    }
    __syncthreads();

    // raw = h3 @ W4 + b4 + equilibrium ; out = sigmoid(gain*raw)
    if (tid < 64) {
        float p = h3[tid] * W4[tid];
        #pragma unroll
        for (int off = 32; off > 0; off >>= 1) p += __shfl_down(p, off);
        if (tid == 0) {
            const float raw = p + b4[0] + equilibrium[0];
            const float z = gain[0] * raw;
            out[row] = 1.f / (1.f + expf(-z));
        }
    }
}

extern "C" void kernel_launch(void* const* d_in, const int* in_sizes, int n_in,
                              void* d_out, int out_size, void* d_ws, size_t ws_size,
                              hipStream_t stream)
{
    const float* x           = (const float*)d_in[0];
    const float* xr          = (const float*)d_in[1];
    const float* fs          = (const float*)d_in[2];
    const float* ft          = (const float*)d_in[3];
    const float* v           = (const float*)d_in[4];
    const float* inv_scales  = (const float*)d_in[5];
    const float* equilibrium = (const float*)d_in[6];
    const float* gain        = (const float*)d_in[7];
    const float* W1          = (const float*)d_in[8];
    const float* b1          = (const float*)d_in[9];
    const float* ln_w        = (const float*)d_in[10];
    const float* ln_b        = (const float*)d_in[11];
    const float* W2          = (const float*)d_in[12];
    const float* b2          = (const float*)d_in[13];
    const float* W3          = (const float*)d_in[14];
    const float* b3          = (const float*)d_in[15];
    const float* W4          = (const float*)d_in[16];
    const float* b4          = (const float*)d_in[17];

    float* partials = (float*)d_ws;   // [B*BPR][8] = 64 KB
    float* out      = (float*)d_out;  // [B]

    invariant_reduce<<<B_ * BPR, TPB, 0, stream>>>(x, xr, fs, ft, v, partials);
    mlp_head<<<B_, 128, 0, stream>>>(partials, inv_scales, equilibrium, gain,
                                     W1, b1, ln_w, ln_b, W2, b2, W3, b3, W4, b4, out);
}

// Round 8
// 538.704 us; speedup vs baseline: 1.0264x; 1.0264x over previous
//
#include <hip/hip_runtime.h>
#include <math.h>

// Problem constants (fixed by the reference: B=256, D=131072, H=128)
constexpr int B_ = 256;
constexpr int D_ = 131072;
constexpr int BPR = 16;                          // blocks per row -> 4096 blocks = 2 clean rounds of 8/CU
constexpr int TPB = 256;                         // threads per reduce block
constexpr int F4_PER_BLOCK = D_ / 4 / BPR;       // 2048 float4 per block per stream
constexpr int NBATCH = F4_PER_BLOCK / TPB;       // 8 iterations, 1 float4/stream/iter

// Native vector type so __builtin_nontemporal_load is applicable (HIP's
// float4 is a class type; clang's builtin needs a scalar/vector).
typedef float f32x4 __attribute__((ext_vector_type(4)));

__device__ __forceinline__ f32x4 nt_load(const f32x4* __restrict__ p) {
    return __builtin_nontemporal_load(p);
}

__device__ __forceinline__ float gelu_exact(float x) {
    // jax.nn.gelu(approximate=False) = 0.5*x*(1+erf(x/sqrt(2)))
    return 0.5f * x * (1.0f + erff(x * 0.7071067811865476f));
}

// ---------------------------------------------------------------------------
// Kernel 1: streaming reduction. Each block handles an 8192-element chunk of
// one row across all 5 arrays, producing 8 partial sums:
//   s0=|d|^2 s1=|v|^2 s2=|fs|^2 s3=|ft|^2 s4=v.d s5=fs.ft s6=v.fs s7=v.ft
//
// History:
//   v3: (256,8) + forced 10-load batch -> scratch spill (WRITE 457 MB), 281us.
//   v4: spill fixed, occ 70%, dur ~180us @ 3.7 TB/s -> occupancy falsified.
//   v5: nontemporal loads: dur 121us, 5.55 TB/s blended (FETCH unchanged:
//       L3 still serves half) — nt un-jammed L1/L2 allocation. BEST.
//   v6: unroll 4: REGRESSED (136us). VGPR pinned at 32 — allocator won't
//       widen the live window; ILP-via-unroll is a dead axis.
//   v7: BPR 8->16 at the v5 config: more resident blocks to probe whether
//       the per-CU request issue rate (not latency hiding, not VALU) is
//       what caps the blended path at 5.55 TB/s. Flat result => v5 is the
//       practical roofline for this access shape.
// ---------------------------------------------------------------------------
__global__ __launch_bounds__(TPB, 8) void invariant_reduce(
    const float* __restrict__ x,
    const float* __restrict__ xr,
    const float* __restrict__ fs,
    const float* __restrict__ ft,
    const float* __restrict__ v,
    float* __restrict__ partials)
{
    const int blk = blockIdx.x;
    const int row = blk / BPR;
    const int chunk = blk % BPR;
    const int tid = threadIdx.x;

    const size_t base = (size_t)row * D_ + (size_t)chunk * (F4_PER_BLOCK * 4);
    const f32x4* __restrict__ x4  = (const f32x4*)(x  + base);
    const f32x4* __restrict__ xr4 = (const f32x4*)(xr + base);
    const f32x4* __restrict__ fs4 = (const f32x4*)(fs + base);
    const f32x4* __restrict__ ft4 = (const f32x4*)(ft + base);
    const f32x4* __restrict__ v4  = (const f32x4*)(v  + base);

    float s0 = 0.f, s1 = 0.f, s2 = 0.f, s3 = 0.f;
    float s4 = 0.f, s5 = 0.f, s6 = 0.f, s7 = 0.f;

    #pragma unroll 2
    for (int it = 0; it < NBATCH; ++it) {
        const int i = it * TPB + tid;
        const f32x4 a = nt_load(&x4[i]);
        const f32x4 b = nt_load(&xr4[i]);
        const f32x4 c = nt_load(&fs4[i]);
        const f32x4 t = nt_load(&ft4[i]);
        const f32x4 w = nt_load(&v4[i]);

        #define ACC(aa, bb, cc, tt, ww)                              \
        {                                                            \
            const float dd = (bb) - (aa);                            \
            s0 = fmaf(dd, dd, s0);                                   \
            s1 = fmaf((ww), (ww), s1);                               \
            s2 = fmaf((cc), (cc), s2);                               \
            s3 = fmaf((tt), (tt), s3);                               \
            s4 = fmaf((ww), dd, s4);                                 \
            s5 = fmaf((cc), (tt), s5);                               \
            s6 = fmaf((ww), (cc), s6);                               \
            s7 = fmaf((ww), (tt), s7);                               \
        }
        ACC(a.x, b.x, c.x, t.x, w.x);
        ACC(a.y, b.y, c.y, t.y, w.y);
        ACC(a.z, b.z, c.z, t.z, w.z);
        ACC(a.w, b.w, c.w, t.w, w.w);
        #undef ACC
    }

    // 64-lane wave reduction for all 8 accumulators
    #pragma unroll
    for (int off = 32; off > 0; off >>= 1) {
        s0 += __shfl_down(s0, off);
        s1 += __shfl_down(s1, off);
        s2 += __shfl_down(s2, off);
        s3 += __shfl_down(s3, off);
        s4 += __shfl_down(s4, off);
        s5 += __shfl_down(s5, off);
        s6 += __shfl_down(s6, off);
        s7 += __shfl_down(s7, off);
    }

    __shared__ float red[TPB / 64][8];
    const int wave = tid >> 6;
    const int lane = tid & 63;
    if (lane == 0) {
        red[wave][0] = s0; red[wave][1] = s1; red[wave][2] = s2; red[wave][3] = s3;
        red[wave][4] = s4; red[wave][5] = s5; red[wave][6] = s6; red[wave][7] = s7;
    }
    __syncthreads();
    if (tid < 8) {
        const float r = red[0][tid] + red[1][tid] + red[2][tid] + red[3][tid];
        partials[(size_t)blk * 8 + tid] = r;
    }
}

// ---------------------------------------------------------------------------
// Kernel 2: one block (128 threads) per row. Sum the partials, form the 8
// invariants, then run the MLP head entirely in LDS/registers.
// ---------------------------------------------------------------------------
__device__ __forceinline__ float block_sum_128(float val, float* scratch2, int tid) {
    #pragma unroll
    for (int off = 32; off > 0; off >>= 1) val += __shfl_down(val, off);
    const int wave = tid >> 6;
    if ((tid & 63) == 0) scratch2[wave] = val;
    __syncthreads();
    const float r = scratch2[0] + scratch2[1];
    __syncthreads();
    return r;
}

__global__ __launch_bounds__(128) void mlp_head(
    const float* __restrict__ partials,
    const float* __restrict__ inv_scales,
    const float* __restrict__ equilibrium,
    const float* __restrict__ gain,
    const float* __restrict__ W1, const float* __restrict__ b1,
    const float* __restrict__ ln_w, const float* __restrict__ ln_b,
    const float* __restrict__ W2, const float* __restrict__ b2,
    const float* __restrict__ W3, const float* __restrict__ b3,
    const float* __restrict__ W4, const float* __restrict__ b4,
    float* __restrict__ out)
{
    const int row = blockIdx.x;
    const int tid = threadIdx.x;

    __shared__ float sums[8];
    __shared__ float s[8];
    __shared__ float h1[128];
    __shared__ float h2[128];
    __shared__ float h3[64];
    __shared__ float scratch[2];

    // Sum the per-chunk partials for this row.
    if (tid < 8) {
        float acc = 0.f;
        const float* p = partials + (size_t)row * BPR * 8 + tid;
        #pragma unroll
        for (int bch = 0; bch < BPR; ++bch) acc += p[bch * 8];
        sums[tid] = acc;
    }
    __syncthreads();

    // Invariants (exactly the reference's _invariants math).
    if (tid < 8) {
        const float eps = 1e-8f;
        const float dn = sqrtf(sums[0]) + eps;
        const float vn = sqrtf(sums[1]) + eps;
        const float sn = sqrtf(sums[2]) + eps;
        const float tn = sqrtf(sums[3]) + eps;
        float val;
        switch (tid) {
            case 0: val = log1pf(dn); break;
            case 1: val = log1pf(vn); break;
            case 2: val = sums[4] / (vn * dn); break;
            case 3: val = sums[5] / (sn * tn); break;
            case 4: val = sums[6] / (vn * sn); break;
            case 5: val = sums[7] / (vn * tn); break;
            case 6: val = log1pf(vn * vn + dn * dn); break;
            default: val = logf(tn / sn); break;
        }
        s[tid] = val * inv_scales[tid];
    }
    __syncthreads();

    // h = s @ W1 + b1  (W1 is [8,128]) ; thread tid owns column tid.
    float acc = b1[tid];
    #pragma unroll
    for (int k = 0; k < 8; ++k) acc = fmaf(s[k], W1[k * 128 + tid], acc);

    // LayerNorm over the 128 columns (two-pass).
    const float mu  = block_sum_128(acc, scratch, tid) * (1.f / 128.f);
    const float dev = acc - mu;
    const float var = block_sum_128(dev * dev, scratch, tid) * (1.f / 128.f);
    const float xn  = dev * rsqrtf(var + 1e-5f) * ln_w[tid] + ln_b[tid];
    h1[tid] = gelu_exact(xn);
    __syncthreads();

    // h2 = gelu(h1 @ W2 + b2), W2 is [128,128]
    float acc2 = b2[tid];
    #pragma unroll 8
    for (int k = 0; k < 128; ++k) acc2 = fmaf(h1[k], W2[k * 128 + tid], acc2);
    h2[tid] = gelu_exact(acc2);
    __syncthreads();

    // h3 = gelu(h2 @ W3 + b3), W3 is [128,64]
    if (tid < 64) {
        float acc3 = b3[tid];
        #pragma unroll 8
        for (int k = 0; k < 128; ++k) acc3 = fmaf(h2[k], W3[k * 64 + tid], acc3);
        h3[tid] = gelu_exact(acc3);
    }
    __syncthreads();

    // raw = h3 @ W4 + b4 + equilibrium ; out = sigmoid(gain*raw)
    if (tid < 64) {
        float p = h3[tid] * W4[tid];
        #pragma unroll
        for (int off = 32; off > 0; off >>= 1) p += __shfl_down(p, off);
        if (tid == 0) {
            const float raw = p + b4[0] + equilibrium[0];
            const float z = gain[0] * raw;
            out[row] = 1.f / (1.f + expf(-z));
        }
    }
}

extern "C" void kernel_launch(void* const* d_in, const int* in_sizes, int n_in,
                              void* d_out, int out_size, void* d_ws, size_t ws_size,
                              hipStream_t stream)
{
    const float* x           = (const float*)d_in[0];
    const float* xr          = (const float*)d_in[1];
    const float* fs          = (const float*)d_in[2];
    const float* ft          = (const float*)d_in[3];
    const float* v           = (const float*)d_in[4];
    const float* inv_scales  = (const float*)d_in[5];
    const float* equilibrium = (const float*)d_in[6];
    const float* gain        = (const float*)d_in[7];
    const float* W1          = (const float*)d_in[8];
    const float* b1          = (const float*)d_in[9];
    const float* ln_w        = (const float*)d_in[10];
    const float* ln_b        = (const float*)d_in[11];
    const float* W2          = (const float*)d_in[12];
    const float* b2          = (const float*)d_in[13];
    const float* W3          = (const float*)d_in[14];
    const float* b3          = (const float*)d_in[15];
    const float* W4          = (const float*)d_in[16];
    const float* b4          = (const float*)d_in[17];

    float* partials = (float*)d_ws;   // [B*BPR][8] = 128 KB
    float* out      = (float*)d_out;  // [B]

    invariant_reduce<<<B_ * BPR, TPB, 0, stream>>>(x, xr, fs, ft, v, partials);
    mlp_head<<<B_, 128, 0, stream>>>(partials, inv_scales, equilibrium, gain,
                                     W1, b1, ln_w, ln_b, W2, b2, W3, b3, W4, b4, out);
}